// Round 3
// baseline (460.311 us; speedup 1.0000x reference)
//
#include <hip/hip_runtime.h>
#include <math.h>

typedef unsigned short u16;
typedef __attribute__((ext_vector_type(8))) short bf16x8;
typedef __attribute__((ext_vector_type(4))) float f32x4;
typedef __attribute__((ext_vector_type(4))) int i32x4;
typedef __attribute__((ext_vector_type(4))) short s16x4;
typedef __attribute__((ext_vector_type(4))) unsigned short u16x4;

#define MFMA16(a,b,c) __builtin_amdgcn_mfma_f32_16x16x32_bf16((a),(b),(c),0,0,0)

__device__ __forceinline__ u16 f2bf(float x){
  unsigned int u = __float_as_uint(x);
  u += 0x7fffu + ((u >> 16) & 1u);   // RNE
  return (u16)(u >> 16);
}
__device__ __forceinline__ float bf2f(u16 x){
  return __uint_as_float(((unsigned)x) << 16);
}
// async global->LDS, 16B per lane. LDS image must be lane-linear.
__device__ __forceinline__ void gload16(const void* g, void* l){
  __builtin_amdgcn_global_load_lds((const __attribute__((address_space(1))) void*)g,
                                   (__attribute__((address_space(3))) void*)l, 16, 0, 0);
}

// ---------------------------------------------------------------------------
// prep: fp32->bf16 + weight transposes + maskP packing.
// maskP[b][rt(16)][col(1024)][p(16)] bf16, p = row-in-16 (MFMA C-layout order).
// grid = 4096 x 256.
// ---------------------------------------------------------------------------
__global__ __launch_bounds__(256) void prep(
    const float* __restrict__ nodes, const float* __restrict__ q1, const float* __restrict__ lastn,
    const float* __restrict__ mask,
    const float* __restrict__ Wqf, const float* __restrict__ Wql, const float* __restrict__ Wk,
    const float* __restrict__ Wv, const float* __restrict__ Wc,
    u16* __restrict__ nodesb, u16* __restrict__ q1b, u16* __restrict__ lastb,
    u16* __restrict__ WtKV, u16* __restrict__ WtQF, u16* __restrict__ WtQL, u16* __restrict__ WtC,
    u16* __restrict__ maskP)
{
  const int tid = blockIdx.x * 256 + threadIdx.x;
  const int NT = 1048576;
  for (int i = tid; i < 4194304; i += NT) {
    float4 v = ((const float4*)nodes)[i];
    u16x4 o; o[0]=f2bf(v.x); o[1]=f2bf(v.y); o[2]=f2bf(v.z); o[3]=f2bf(v.w);
    *(u16x4*)&nodesb[i*4] = o;
  }
  {
    float4 v = ((const float4*)q1)[tid];
    u16x4 o; o[0]=f2bf(v.x); o[1]=f2bf(v.y); o[2]=f2bf(v.z); o[3]=f2bf(v.w);
    *(u16x4*)&q1b[tid*4] = o;
    v = ((const float4*)lastn)[tid];
    o[0]=f2bf(v.x); o[1]=f2bf(v.y); o[2]=f2bf(v.z); o[3]=f2bf(v.w);
    *(u16x4*)&lastb[tid*4] = o;
  }
  if (tid < 262144) {
    int n = tid >> 9, k = tid & 511;
    WtQF[tid] = f2bf(Wqf[k*512 + n]);
    WtQL[tid] = f2bf(Wql[k*512 + n]);
    WtC[tid]  = f2bf(Wc[k*512 + n]);
  }
  if (tid < 524288) {
    int n = tid >> 9, k = tid & 511;
    WtKV[tid] = f2bf(n < 512 ? Wk[k*512 + n] : Wv[k*512 + (n-512)]);
  }
  if (tid < 524288) {  // maskP: tid = (b*16 + rt)*1024 + c
    int brt = tid >> 10, c = tid & 1023;
    const float* mp = mask + (brt*16)*1024 + c;
    u16 vals[16];
    #pragma unroll
    for (int p=0;p<16;p++) vals[p] = f2bf(mp[p*1024]);
    *(i32x4*)&maskP[tid*16]     = *(i32x4*)&vals[0];
    *(i32x4*)&maskP[tid*16 + 8] = *(i32x4*)&vals[8];
  }
}

// ---------------------------------------------------------------------------
// K|V projection GEMM, 128x128 tile, BK=64 (8 iters, 32 MFMA/wave/barrier).
// grid = 2048 (256 m x 8 n).
// ---------------------------------------------------------------------------
__global__ __launch_bounds__(256) void gemm_kv(const u16* __restrict__ A, const u16* __restrict__ Bw,
                                               u16* __restrict__ Kout, u16* __restrict__ Vout)
{
  const int mb = blockIdx.x & 255, nb = blockIdx.x >> 8;
  const int t = threadIdx.x, w = t >> 6, l = t & 63, q = l >> 4, ln = l & 15;
  const int wm = (w >> 1) * 64, wn = (w & 1) * 64;
  __shared__ u16 As[8192];   // [koct(8)][row(128)][8]
  __shared__ u16 Bs[8192];
  f32x4 acc[4][4];
  #pragma unroll
  for (int i=0;i<4;i++)
    #pragma unroll
    for (int j=0;j<4;j++)
      #pragma unroll
      for (int r=0;r<4;r++) acc[i][j][r] = 0.f;
  const int m0 = mb*128, n0 = nb*128;
  for (int kc = 0; kc < 8; kc++) {
    __syncthreads();
    #pragma unroll
    for (int c=0;c<4;c++) {
      int chunk = t + 256*c;
      int row = chunk & 127, ko = chunk >> 7;
      gload16(&A[(m0+row)*512 + kc*64 + ko*8], &As[chunk*8]);
      gload16(&Bw[(n0+row)*512 + kc*64 + ko*8], &Bs[chunk*8]);
    }
    __syncthreads();
    #pragma unroll
    for (int ko=0;ko<2;ko++) {
      bf16x8 af[4], bfr[4];
      #pragma unroll
      for (int i=0;i<4;i++) af[i] = *(bf16x8*)&As[((ko*4+q)*128 + wm + i*16 + ln)*8];
      #pragma unroll
      for (int j=0;j<4;j++) bfr[j] = *(bf16x8*)&Bs[((ko*4+q)*128 + wn + j*16 + ln)*8];
      #pragma unroll
      for (int i=0;i<4;i++)
        #pragma unroll
        for (int j=0;j<4;j++)
          acc[i][j] = MFMA16(af[i], bfr[j], acc[i][j]);
    }
  }
  const int bb = m0 >> 10;
  #pragma unroll
  for (int i=0;i<4;i++) {
    int gm = m0 + wm + i*16 + q*4;
    int m = gm & 1023;
    #pragma unroll
    for (int j=0;j<4;j++) {
      int gn = n0 + wn + j*16 + ln;
      if (gn < 512) {
        int h = gn >> 5, d = gn & 31;
        u16* kp = Kout + ((bb*16 + h)*1024 + m)*32 + d;
        #pragma unroll
        for (int r=0;r<4;r++) kp[r*32] = f2bf(acc[i][j][r]);
      } else {
        int n2 = gn - 512, h = n2 >> 5, d = n2 & 31;
        u16* vp = Vout + ((bb*16 + h)*32 + d)*1024 + m;
        s16x4 o;
        #pragma unroll
        for (int r=0;r<4;r++) o[r] = (short)f2bf(acc[i][j][r]);
        *(s16x4*)vp = o;
      }
    }
  }
}

// ---------------------------------------------------------------------------
// Q projection, 64x64 tile, BK=64. Q = (q1@Wqf + last@Wql) * (1/sqrt(32)).
// grid = 1024 (128 m x 8 n).
// ---------------------------------------------------------------------------
__global__ __launch_bounds__(256) void gemm_q(const u16* __restrict__ A1, const u16* __restrict__ A2,
                                              const u16* __restrict__ B1, const u16* __restrict__ B2,
                                              u16* __restrict__ Qout)
{
  const int mb = blockIdx.x >> 3, nb = blockIdx.x & 7;
  const int t = threadIdx.x, w = t >> 6, l = t & 63, q = l >> 4, ln = l & 15;
  const int wm = (w >> 1) * 32, wn = (w & 1) * 32;
  __shared__ u16 As[4096];   // [koct(8)][row(64)][8]
  __shared__ u16 Bs[4096];
  f32x4 acc[2][2];
  #pragma unroll
  for (int i=0;i<2;i++)
    #pragma unroll
    for (int j=0;j<2;j++)
      #pragma unroll
      for (int r=0;r<4;r++) acc[i][j][r] = 0.f;
  const int m0 = mb*64, n0 = nb*64;
  for (int kc = 0; kc < 16; kc++) {
    const u16* Ap = (kc < 8) ? A1 : A2;
    const u16* Bp = (kc < 8) ? B1 : B2;
    const int k0 = (kc & 7) * 64;
    __syncthreads();
    #pragma unroll
    for (int c=0;c<2;c++) {
      int chunk = t + 256*c;
      int row = chunk & 63, ko = chunk >> 6;
      gload16(&Ap[(m0+row)*512 + k0 + ko*8], &As[chunk*8]);
      gload16(&Bp[(n0+row)*512 + k0 + ko*8], &Bs[chunk*8]);
    }
    __syncthreads();
    #pragma unroll
    for (int ko=0;ko<2;ko++) {
      bf16x8 af[2], bfr[2];
      #pragma unroll
      for (int i=0;i<2;i++) af[i] = *(bf16x8*)&As[((ko*4+q)*64 + wm + i*16 + ln)*8];
      #pragma unroll
      for (int j=0;j<2;j++) bfr[j] = *(bf16x8*)&Bs[((ko*4+q)*64 + wn + j*16 + ln)*8];
      #pragma unroll
      for (int i=0;i<2;i++)
        #pragma unroll
        for (int j=0;j<2;j++)
          acc[i][j] = MFMA16(af[i], bfr[j], acc[i][j]);
    }
  }
  const float sc = 0.17677669529663687f;
  #pragma unroll
  for (int i=0;i<2;i++) {
    int gm = m0 + wm + i*16 + q*4;
    int bb = gm >> 8, pm = gm & 255;
    #pragma unroll
    for (int j=0;j<2;j++) {
      int gn = n0 + wn + j*16 + ln;
      int h = gn >> 5, d = gn & 31;
      u16* qp = Qout + ((bb*16 + h)*256 + pm)*32 + d;
      #pragma unroll
      for (int r=0;r<4;r++) qp[r*32] = f2bf(acc[i][j][r]*sc);
    }
  }
}

// ---------------------------------------------------------------------------
// Fused attention per (b, h, pomo64). grid = 2048, 4 waves.
// ---------------------------------------------------------------------------
__global__ __launch_bounds__(256) void attn(const u16* __restrict__ Qg, const u16* __restrict__ Kg,
                                            const u16* __restrict__ Vtg, const u16* __restrict__ maskP,
                                            u16* __restrict__ Og)
{
  const int bid = blockIdx.x;
  const int pt = bid & 3, h = (bid >> 2) & 15, bb = bid >> 6;
  const int t = threadIdx.x, w = t >> 6, l = t & 63, q = l >> 4, ln = l & 15;
  __shared__ u16 Qs[2048];     // [qk(4)][row(64)][8]
  __shared__ u16 Ks[4096];     // [qk(4)][m(128)][8]
  __shared__ u16 Vs[4096];     // [moct(16)][d(32)][8]
  __shared__ u16 Ps[4*640];    // per wave [16][40]
  u16* Pw = &Ps[w*640];
  const int qbase = ((bb*16 + h)*256 + pt*64)*32;
  gload16(&Qg[qbase + (t & 63)*32 + (t >> 6)*8], &Qs[t*8]);
  const int kbase = (bb*16 + h)*1024*32;
  const int vbase = (bb*16 + h)*32*1024;
  float rs[4] = {0.f,0.f,0.f,0.f};
  f32x4 oacc[2];
  #pragma unroll
  for (int dt=0;dt<2;dt++)
    #pragma unroll
    for (int r=0;r<4;r++) oacc[dt][r] = 0.f;
  __syncthreads();
  const bf16x8 aq = *(bf16x8*)&Qs[(q*64 + w*16 + ln)*8];
  const u16* mrow = maskP + (bb*16 + pt*4 + w)*16384 + q*4;
  for (int mc = 0; mc < 8; mc++) {
    __syncthreads();
    gload16(&Kg[kbase + (mc*128 + (t & 127))*32 + (t >> 7)*8],       &Ks[t*8]);
    gload16(&Kg[kbase + (mc*128 + (t & 127))*32 + ((t >> 7)+2)*8],   &Ks[(t+256)*8]);
    gload16(&Vtg[vbase + (t & 31)*1024 + mc*128 + (t >> 5)*8],       &Vs[t*8]);
    gload16(&Vtg[vbase + (t & 31)*1024 + mc*128 + ((t >> 5)+8)*8],   &Vs[(t+256)*8]);
    u16x4 mq[8];
    #pragma unroll
    for (int j2=0;j2<8;j2++)
      mq[j2] = *(const u16x4*)&mrow[(mc*128 + j2*16 + ln)*16];
    __syncthreads();
    #pragma unroll
    for (int ch=0; ch<4; ch++) {
      bf16x8 bk0 = *(bf16x8*)&Ks[(q*128 + (ch*2+0)*16 + ln)*8];
      bf16x8 bk1 = *(bf16x8*)&Ks[(q*128 + (ch*2+1)*16 + ln)*8];
      f32x4 zz = {0.f,0.f,0.f,0.f};
      f32x4 s0 = MFMA16(aq, bk0, zz);
      f32x4 s1 = MFMA16(aq, bk1, zz);
      #pragma unroll
      for (int r=0;r<4;r++) {
        float e0 = __expf(s0[r] + bf2f(mq[ch*2+0][r]));
        float e1 = __expf(s1[r] + bf2f(mq[ch*2+1][r]));
        rs[r] += e0 + e1;
        Pw[(q*4+r)*40 + ln]      = f2bf(e0);
        Pw[(q*4+r)*40 + 16 + ln] = f2bf(e1);
      }
      bf16x8 ap  = *(bf16x8*)&Pw[ln*40 + q*8];
      bf16x8 bv0 = *(bf16x8*)&Vs[((ch*4+q)*32 + ln)*8];
      bf16x8 bv1 = *(bf16x8*)&Vs[((ch*4+q)*32 + 16 + ln)*8];
      oacc[0] = MFMA16(ap, bv0, oacc[0]);
      oacc[1] = MFMA16(ap, bv1, oacc[1]);
    }
  }
  #pragma unroll
  for (int r=0;r<4;r++) {
    float v = rs[r];
    v += __shfl_xor(v,1); v += __shfl_xor(v,2); v += __shfl_xor(v,4); v += __shfl_xor(v,8);
    rs[r] = __builtin_amdgcn_rcpf(v);
  }
  const int orow = bb*256 + pt*64 + w*16 + q*4;
  #pragma unroll
  for (int dt=0;dt<2;dt++)
    #pragma unroll
    for (int r=0;r<4;r++)
      Og[(orow + r)*512 + h*32 + dt*16 + ln] = f2bf(oacc[dt][r]*rs[r]);
}

// ---------------------------------------------------------------------------
// Combine GEMM 64x64, BK=64: mh = oc @ Wc + bias. grid = 1024.
// ---------------------------------------------------------------------------
__global__ __launch_bounds__(256) void gemm_cmb(const u16* __restrict__ A, const u16* __restrict__ Bw,
                                                const float* __restrict__ bias, u16* __restrict__ Mout)
{
  const int mb = blockIdx.x >> 3, nb = blockIdx.x & 7;
  const int t = threadIdx.x, w = t >> 6, l = t & 63, q = l >> 4, ln = l & 15;
  const int wm = (w >> 1) * 32, wn = (w & 1) * 32;
  __shared__ u16 As[4096];
  __shared__ u16 Bs[4096];
  f32x4 acc[2][2];
  #pragma unroll
  for (int i=0;i<2;i++)
    #pragma unroll
    for (int j=0;j<2;j++)
      #pragma unroll
      for (int r=0;r<4;r++) acc[i][j][r] = 0.f;
  const int m0 = mb*64, n0 = nb*64;
  for (int kc = 0; kc < 8; kc++) {
    __syncthreads();
    #pragma unroll
    for (int c=0;c<2;c++) {
      int chunk = t + 256*c;
      int row = chunk & 63, ko = chunk >> 6;
      gload16(&A[(m0+row)*512 + kc*64 + ko*8], &As[chunk*8]);
      gload16(&Bw[(n0+row)*512 + kc*64 + ko*8], &Bs[chunk*8]);
    }
    __syncthreads();
    #pragma unroll
    for (int ko=0;ko<2;ko++) {
      bf16x8 af[2], bfr[2];
      #pragma unroll
      for (int i=0;i<2;i++) af[i] = *(bf16x8*)&As[((ko*4+q)*64 + wm + i*16 + ln)*8];
      #pragma unroll
      for (int j=0;j<2;j++) bfr[j] = *(bf16x8*)&Bs[((ko*4+q)*64 + wn + j*16 + ln)*8];
      #pragma unroll
      for (int i=0;i<2;i++)
        #pragma unroll
        for (int j=0;j<2;j++)
          acc[i][j] = MFMA16(af[i], bfr[j], acc[i][j]);
    }
  }
  #pragma unroll
  for (int i=0;i<2;i++) {
    int gmb = m0 + wm + i*16 + q*4;
    #pragma unroll
    for (int j=0;j<2;j++) {
      int gn = n0 + wn + j*16 + ln;
      float bv = bias[gn];
      #pragma unroll
      for (int r=0;r<4;r++) Mout[(gmb + r)*512 + gn] = f2bf(acc[i][j][r] + bv);
    }
  }
}

// ---------------------------------------------------------------------------
// final1 (fused normalize): score2 = mh @ nodes^T / sqrt(512), 10*tanh + mask,
// softmax over the full row held in-block -> store probs directly.
// grid = 512 (32 b x 16 row-tiles), 512 threads (8 waves x 128 cols).
// ---------------------------------------------------------------------------
__global__ __launch_bounds__(512) void final1(const u16* __restrict__ mhb, const u16* __restrict__ nodesb,
                                              const u16* __restrict__ maskP, float* __restrict__ out)
{
  const int bid = blockIdx.x;
  const int rt = bid & 15, bb = bid >> 4;
  const int t = threadIdx.x, w = t >> 6, l = t & 63, q = l >> 4, ln = l & 15;
  __shared__ u16 As[8192];      // [koct(64)][row(16)][8]
  __shared__ float rsL[8][16];
  const int abase = (bb*256 + rt*16)*512;
  #pragma unroll
  for (int c=0;c<2;c++) {
    int chunk = t + 512*c;
    gload16(&mhb[abase + (chunk & 15)*512 + (chunk >> 4)*8], &As[chunk*8]);
  }
  __syncthreads();
  float rloc[4] = {0.f,0.f,0.f,0.f};
  const int nbase = bb*524288;
  f32x4 acc[8];
  #pragma unroll
  for (int ct=0;ct<8;ct++)
    #pragma unroll
    for (int r=0;r<4;r++) acc[ct][r] = 0.f;
  for (int kc=0;kc<16;kc++) {
    bf16x8 af = *(bf16x8*)&As[((kc*4 + q)*16 + ln)*8];
    #pragma unroll
    for (int ct=0;ct<8;ct++) {
      int col = w*128 + ct*16 + ln;
      bf16x8 bfr = *(const bf16x8*)&nodesb[nbase + col*512 + kc*32 + q*8];
      acc[ct] = MFMA16(af, bfr, acc[ct]);
    }
  }
  const float c2 = 0.08838834764831843f;   // 2/sqrt(512)
  const int prow_base = bb*256 + rt*16;
  #pragma unroll
  for (int ct=0;ct<8;ct++) {
    int col0 = w*128 + ct*16 + ln;
    u16x4 mv = *(const u16x4*)&maskP[((bb*16 + rt)*1024 + col0)*16 + q*4];
    #pragma unroll
    for (int r=0;r<4;r++) {
      float x = acc[ct][r] * c2;
      x = fminf(fmaxf(x, -30.f), 30.f);
      float e2 = __expf(x);
      float lg = 10.f*(e2 - 1.f)*__builtin_amdgcn_rcpf(e2 + 1.f) + bf2f(mv[r]);
      float e = __expf(lg);
      rloc[r] += e;
      acc[ct][r] = e;
    }
  }
  #pragma unroll
  for (int r=0;r<4;r++) {
    float v = rloc[r];
    v += __shfl_xor(v,1); v += __shfl_xor(v,2); v += __shfl_xor(v,4); v += __shfl_xor(v,8);
    rloc[r] = v;
  }
  if (ln == 0) {
    #pragma unroll
    for (int r=0;r<4;r++) rsL[w][q*4 + r] = rloc[r];
  }
  __syncthreads();
  float inv[4];
  #pragma unroll
  for (int r=0;r<4;r++) {
    float tot = 0.f;
    #pragma unroll
    for (int ww=0;ww<8;ww++) tot += rsL[ww][q*4 + r];
    inv[r] = __builtin_amdgcn_rcpf(tot);
  }
  #pragma unroll
  for (int ct=0;ct<8;ct++) {
    int col0 = w*128 + ct*16 + ln;
    #pragma unroll
    for (int r=0;r<4;r++)
      out[(prow_base + q*4 + r)*1024 + col0] = acc[ct][r]*inv[r];
  }
}

extern "C" void kernel_launch(void* const* d_in, const int* in_sizes, int n_in,
                              void* d_out, int out_size, void* d_ws, size_t ws_size,
                              hipStream_t stream)
{
  (void)in_sizes; (void)n_in; (void)out_size; (void)ws_size;
  const float* nodes = (const float*)d_in[0];
  const float* q1    = (const float*)d_in[1];
  const float* lastn = (const float*)d_in[2];
  const float* mask  = (const float*)d_in[3];
  const float* Wqf   = (const float*)d_in[4];
  const float* Wql   = (const float*)d_in[5];
  const float* Wk    = (const float*)d_in[6];
  const float* Wv    = (const float*)d_in[7];
  const float* Wc    = (const float*)d_in[8];
  const float* bias  = (const float*)d_in[9];
  float* out = (float*)d_out;

  char* p = (char*)d_ws;
  u16* nodesb = (u16*)p; p += 33554432;   // [32][1024][512] bf16
  u16* q1b    = (u16*)p; p += 8388608;    // [32][256][512]
  u16* lastb  = (u16*)p; p += 8388608;
  u16* WtKV   = (u16*)p; p += 1048576;    // [1024][512]
  u16* WtQF   = (u16*)p; p += 524288;
  u16* WtQL   = (u16*)p; p += 524288;
  u16* WtC    = (u16*)p; p += 524288;
  u16* Kt     = (u16*)p; p += 33554432;   // K [32][16][1024][32]
  u16* Vt     = (u16*)p; p += 33554432;   // V^T [32][16][32][1024]
  u16* Qh     = (u16*)p; p += 8388608;    // Q(scaled) [32][16][256][32]
  u16* maskP  = (u16*)p; p += 16777216;   // [32][16][1024][16] bf16
  u16* oc  = lastb;   // dead after gemm_q
  u16* mhb = q1b;     // dead after gemm_q

  prep<<<4096, 256, 0, stream>>>(nodes, q1, lastn, mask, Wqf, Wql, Wk, Wv, Wc,
                                 nodesb, q1b, lastb, WtKV, WtQF, WtQL, WtC, maskP);
  gemm_kv<<<2048, 256, 0, stream>>>(nodesb, WtKV, Kt, Vt);
  gemm_q<<<1024, 256, 0, stream>>>(q1b, lastb, WtQF, WtQL, Qh);
  attn<<<2048, 256, 0, stream>>>(Qh, Kt, Vt, maskP, oc);
  gemm_cmb<<<1024, 256, 0, stream>>>(oc, WtC, bias, mhb);
  final1<<<512, 512, 0, stream>>>(mhb, nodesb, maskP, out);
}

// Round 4
// 455.593 us; speedup vs baseline: 1.0104x; 1.0104x over previous
//
#include <hip/hip_runtime.h>
#include <math.h>

typedef unsigned short u16;
typedef __attribute__((ext_vector_type(8))) short bf16x8;
typedef __attribute__((ext_vector_type(4))) float f32x4;
typedef __attribute__((ext_vector_type(4))) int i32x4;
typedef __attribute__((ext_vector_type(4))) short s16x4;
typedef __attribute__((ext_vector_type(4))) unsigned short u16x4;

#define MFMA16(a,b,c) __builtin_amdgcn_mfma_f32_16x16x32_bf16((a),(b),(c),0,0,0)

__device__ __forceinline__ u16 f2bf(float x){
  unsigned int u = __float_as_uint(x);
  u += 0x7fffu + ((u >> 16) & 1u);   // RNE
  return (u16)(u >> 16);
}
__device__ __forceinline__ float bf2f(u16 x){
  return __uint_as_float(((unsigned)x) << 16);
}
// async global->LDS, 16B per lane. LDS image must be lane-linear.
__device__ __forceinline__ void gload16(const void* g, void* l){
  __builtin_amdgcn_global_load_lds((const __attribute__((address_space(1))) void*)g,
                                   (__attribute__((address_space(3))) void*)l, 16, 0, 0);
}

// ---------------------------------------------------------------------------
// prep: fp32->bf16 + weight transposes + maskP packing.
// maskP[b][rt(16)][col(1024)][p(16)] bf16, p = row-in-16 (MFMA C-layout order).
// grid = 4096 x 256.
// ---------------------------------------------------------------------------
__global__ __launch_bounds__(256) void prep(
    const float* __restrict__ nodes, const float* __restrict__ q1, const float* __restrict__ lastn,
    const float* __restrict__ mask,
    const float* __restrict__ Wqf, const float* __restrict__ Wql, const float* __restrict__ Wk,
    const float* __restrict__ Wv, const float* __restrict__ Wc,
    u16* __restrict__ nodesb, u16* __restrict__ q1b, u16* __restrict__ lastb,
    u16* __restrict__ WtKV, u16* __restrict__ WtQF, u16* __restrict__ WtQL, u16* __restrict__ WtC,
    u16* __restrict__ maskP)
{
  const int tid = blockIdx.x * 256 + threadIdx.x;
  const int NT = 1048576;
  for (int i = tid; i < 4194304; i += NT) {
    float4 v = ((const float4*)nodes)[i];
    u16x4 o; o[0]=f2bf(v.x); o[1]=f2bf(v.y); o[2]=f2bf(v.z); o[3]=f2bf(v.w);
    *(u16x4*)&nodesb[i*4] = o;
  }
  {
    float4 v = ((const float4*)q1)[tid];
    u16x4 o; o[0]=f2bf(v.x); o[1]=f2bf(v.y); o[2]=f2bf(v.z); o[3]=f2bf(v.w);
    *(u16x4*)&q1b[tid*4] = o;
    v = ((const float4*)lastn)[tid];
    o[0]=f2bf(v.x); o[1]=f2bf(v.y); o[2]=f2bf(v.z); o[3]=f2bf(v.w);
    *(u16x4*)&lastb[tid*4] = o;
  }
  if (tid < 262144) {
    int n = tid >> 9, k = tid & 511;
    WtQF[tid] = f2bf(Wqf[k*512 + n]);
    WtQL[tid] = f2bf(Wql[k*512 + n]);
    WtC[tid]  = f2bf(Wc[k*512 + n]);
  }
  if (tid < 524288) {
    int n = tid >> 9, k = tid & 511;
    WtKV[tid] = f2bf(n < 512 ? Wk[k*512 + n] : Wv[k*512 + (n-512)]);
  }
  if (tid < 524288) {  // maskP: tid = (b*16 + rt)*1024 + c
    int brt = tid >> 10, c = tid & 1023;
    const float* mp = mask + (brt*16)*1024 + c;
    u16 vals[16];
    #pragma unroll
    for (int p=0;p<16;p++) vals[p] = f2bf(mp[p*1024]);
    *(i32x4*)&maskP[tid*16]     = *(i32x4*)&vals[0];
    *(i32x4*)&maskP[tid*16 + 8] = *(i32x4*)&vals[8];
  }
}

// ---------------------------------------------------------------------------
// K|V projection GEMM, 128x128 tile, BK=32 double-buffered, nb-fastest block
// order (8 A-sharing blocks adjacent), LDS-transpose epilogue -> coalesced
// 16B stores. grid = 2048 (mb = bid>>3, nb = bid&7).
// ---------------------------------------------------------------------------
__global__ __launch_bounds__(256) void gemm_kv(const u16* __restrict__ A, const u16* __restrict__ Bw,
                                               u16* __restrict__ Kout, u16* __restrict__ Vout)
{
  const int mb = blockIdx.x >> 3, nb = blockIdx.x & 7;
  const int t = threadIdx.x, w = t >> 6, l = t & 63, q = l >> 4, ln = l & 15;
  const int wm = (w >> 1) * 64, wn = (w & 1) * 64;
  // buffers: buf b at smem + b*8192 (A 4096 u16, then B 4096 u16).
  // epilogue reuses smem as Lt[col(128)][row pad 140].
  __shared__ u16 smem[17920];
  f32x4 acc[4][4];
  #pragma unroll
  for (int i=0;i<4;i++)
    #pragma unroll
    for (int j=0;j<4;j++)
      #pragma unroll
      for (int r=0;r<4;r++) acc[i][j][r] = 0.f;
  const int m0 = mb*128, n0 = nb*128;

  // stage tile kc into buffer b: LDS layout [koct(4)][row(128)][8]
  #define STAGE_KV(kc_, b_) { \
    u16* sa = smem + (b_)*8192; \
    u16* sb = sa + 4096; \
    _Pragma("unroll") \
    for (int c=0;c<2;c++){ \
      int chunk = c*256 + t; \
      int ko = chunk >> 7, r_ = chunk & 127; \
      gload16(&A[(m0+r_)*512 + (kc_)*32 + ko*8], &sa[chunk*8]); \
      gload16(&Bw[(n0+r_)*512 + (kc_)*32 + ko*8], &sb[chunk*8]); \
    } }

  STAGE_KV(0, 0);
  for (int kc = 0; kc < 16; kc++) {
    __syncthreads();                 // drains this wave's loads for tile kc
    if (kc < 15) STAGE_KV(kc+1, (kc+1)&1);   // prefetch overlaps compute below
    const u16* sa = smem + (kc&1)*8192;
    const u16* sb = sa + 4096;
    bf16x8 af[4], bfr[4];
    #pragma unroll
    for (int i=0;i<4;i++) af[i] = *(bf16x8*)&sa[(q*128 + wm + i*16 + ln)*8];
    #pragma unroll
    for (int j=0;j<4;j++) bfr[j] = *(bf16x8*)&sb[(q*128 + wn + j*16 + ln)*8];
    #pragma unroll
    for (int i=0;i<4;i++)
      #pragma unroll
      for (int j=0;j<4;j++)
        acc[i][j] = MFMA16(af[i], bfr[j], acc[i][j]);
  }
  #undef STAGE_KV

  // ---- epilogue: transpose via LDS, then coalesced stores ----
  __syncthreads();
  #pragma unroll
  for (int i=0;i<4;i++) {
    #pragma unroll
    for (int j=0;j<4;j++) {
      s16x4 o;
      #pragma unroll
      for (int r=0;r<4;r++) o[r] = (short)f2bf(acc[i][j][r]);
      *(s16x4*)&smem[(wn + j*16 + ln)*140 + wm + i*16 + q*4] = o;
    }
  }
  __syncthreads();
  const int bb_ = mb >> 3, mloc = (mb & 7)*128;
  if (nb < 4) {
    // K[bh][m][d]: per head (hl = w), 4096-elem contiguous region
    u16* base = Kout + ((bb_*16 + nb*4 + w)*1024 + mloc)*32;
    #pragma unroll
    for (int it=0; it<8; it++) {
      int idx = it*512 + l*8;              // 0..4095
      int m_ = idx >> 5, d0 = idx & 31;    // d0 = (l&3)*8
      int col = w*32 + d0;
      u16 v[8];
      #pragma unroll
      for (int dd=0;dd<8;dd++) v[dd] = smem[(col+dd)*140 + m_];
      *(i32x4*)&base[idx] = *(i32x4*)&v[0];
    }
  } else {
    // V^T[bh][d][m]: per wave head hl = w, rows contiguous in m
    u16* base = Vout + (((bb_*16 + (nb-4)*4 + w)*32))*1024 + mloc;
    #pragma unroll
    for (int it=0; it<8; it++) {
      int d_ = it*4 + (l >> 4);            // 0..31
      int mc_ = (l & 15)*8;                // 0..120
      *(i32x4*)&base[d_*1024 + mc_] = *(i32x4*)&smem[(w*32 + d_)*140 + mc_];
    }
  }
}

// ---------------------------------------------------------------------------
// Q projection, 64x64 tile, BK=64. Q = (q1@Wqf + last@Wql) * (1/sqrt(32)).
// grid = 1024 (128 m x 8 n).
// ---------------------------------------------------------------------------
__global__ __launch_bounds__(256) void gemm_q(const u16* __restrict__ A1, const u16* __restrict__ A2,
                                              const u16* __restrict__ B1, const u16* __restrict__ B2,
                                              u16* __restrict__ Qout)
{
  const int mb = blockIdx.x >> 3, nb = blockIdx.x & 7;
  const int t = threadIdx.x, w = t >> 6, l = t & 63, q = l >> 4, ln = l & 15;
  const int wm = (w >> 1) * 32, wn = (w & 1) * 32;
  __shared__ u16 As[4096];   // [koct(8)][row(64)][8]
  __shared__ u16 Bs[4096];
  f32x4 acc[2][2];
  #pragma unroll
  for (int i=0;i<2;i++)
    #pragma unroll
    for (int j=0;j<2;j++)
      #pragma unroll
      for (int r=0;r<4;r++) acc[i][j][r] = 0.f;
  const int m0 = mb*64, n0 = nb*64;
  for (int kc = 0; kc < 16; kc++) {
    const u16* Ap = (kc < 8) ? A1 : A2;
    const u16* Bp = (kc < 8) ? B1 : B2;
    const int k0 = (kc & 7) * 64;
    __syncthreads();
    #pragma unroll
    for (int c=0;c<2;c++) {
      int chunk = t + 256*c;
      int row = chunk & 63, ko = chunk >> 6;
      gload16(&Ap[(m0+row)*512 + k0 + ko*8], &As[chunk*8]);
      gload16(&Bp[(n0+row)*512 + k0 + ko*8], &Bs[chunk*8]);
    }
    __syncthreads();
    #pragma unroll
    for (int ko=0;ko<2;ko++) {
      bf16x8 af[2], bfr[2];
      #pragma unroll
      for (int i=0;i<2;i++) af[i] = *(bf16x8*)&As[((ko*4+q)*64 + wm + i*16 + ln)*8];
      #pragma unroll
      for (int j=0;j<2;j++) bfr[j] = *(bf16x8*)&Bs[((ko*4+q)*64 + wn + j*16 + ln)*8];
      #pragma unroll
      for (int i=0;i<2;i++)
        #pragma unroll
        for (int j=0;j<2;j++)
          acc[i][j] = MFMA16(af[i], bfr[j], acc[i][j]);
    }
  }
  const float sc = 0.17677669529663687f;
  #pragma unroll
  for (int i=0;i<2;i++) {
    int gm = m0 + wm + i*16 + q*4;
    int bb = gm >> 8, pm = gm & 255;
    #pragma unroll
    for (int j=0;j<2;j++) {
      int gn = n0 + wn + j*16 + ln;
      int h = gn >> 5, d = gn & 31;
      u16* qp = Qout + ((bb*16 + h)*256 + pm)*32 + d;
      #pragma unroll
      for (int r=0;r<4;r++) qp[r*32] = f2bf(acc[i][j][r]*sc);
    }
  }
}

// ---------------------------------------------------------------------------
// Fused attention per (b, h, pomo64). grid = 2048, 4 waves.
// ---------------------------------------------------------------------------
__global__ __launch_bounds__(256) void attn(const u16* __restrict__ Qg, const u16* __restrict__ Kg,
                                            const u16* __restrict__ Vtg, const u16* __restrict__ maskP,
                                            u16* __restrict__ Og)
{
  const int bid = blockIdx.x;
  const int pt = bid & 3, h = (bid >> 2) & 15, bb = bid >> 6;
  const int t = threadIdx.x, w = t >> 6, l = t & 63, q = l >> 4, ln = l & 15;
  __shared__ u16 Qs[2048];     // [qk(4)][row(64)][8]
  __shared__ u16 Ks[4096];     // [qk(4)][m(128)][8]
  __shared__ u16 Vs[4096];     // [moct(16)][d(32)][8]
  __shared__ u16 Ps[4*640];    // per wave [16][40]
  u16* Pw = &Ps[w*640];
  const int qbase = ((bb*16 + h)*256 + pt*64)*32;
  gload16(&Qg[qbase + (t & 63)*32 + (t >> 6)*8], &Qs[t*8]);
  const int kbase = (bb*16 + h)*1024*32;
  const int vbase = (bb*16 + h)*32*1024;
  float rs[4] = {0.f,0.f,0.f,0.f};
  f32x4 oacc[2];
  #pragma unroll
  for (int dt=0;dt<2;dt++)
    #pragma unroll
    for (int r=0;r<4;r++) oacc[dt][r] = 0.f;
  __syncthreads();
  const bf16x8 aq = *(bf16x8*)&Qs[(q*64 + w*16 + ln)*8];
  const u16* mrow = maskP + (bb*16 + pt*4 + w)*16384 + q*4;
  for (int mc = 0; mc < 8; mc++) {
    __syncthreads();
    gload16(&Kg[kbase + (mc*128 + (t & 127))*32 + (t >> 7)*8],       &Ks[t*8]);
    gload16(&Kg[kbase + (mc*128 + (t & 127))*32 + ((t >> 7)+2)*8],   &Ks[(t+256)*8]);
    gload16(&Vtg[vbase + (t & 31)*1024 + mc*128 + (t >> 5)*8],       &Vs[t*8]);
    gload16(&Vtg[vbase + (t & 31)*1024 + mc*128 + ((t >> 5)+8)*8],   &Vs[(t+256)*8]);
    u16x4 mq[8];
    #pragma unroll
    for (int j2=0;j2<8;j2++)
      mq[j2] = *(const u16x4*)&mrow[(mc*128 + j2*16 + ln)*16];
    __syncthreads();
    #pragma unroll
    for (int ch=0; ch<4; ch++) {
      bf16x8 bk0 = *(bf16x8*)&Ks[(q*128 + (ch*2+0)*16 + ln)*8];
      bf16x8 bk1 = *(bf16x8*)&Ks[(q*128 + (ch*2+1)*16 + ln)*8];
      f32x4 zz = {0.f,0.f,0.f,0.f};
      f32x4 s0 = MFMA16(aq, bk0, zz);
      f32x4 s1 = MFMA16(aq, bk1, zz);
      #pragma unroll
      for (int r=0;r<4;r++) {
        float e0 = __expf(s0[r] + bf2f(mq[ch*2+0][r]));
        float e1 = __expf(s1[r] + bf2f(mq[ch*2+1][r]));
        rs[r] += e0 + e1;
        Pw[(q*4+r)*40 + ln]      = f2bf(e0);
        Pw[(q*4+r)*40 + 16 + ln] = f2bf(e1);
      }
      bf16x8 ap  = *(bf16x8*)&Pw[ln*40 + q*8];
      bf16x8 bv0 = *(bf16x8*)&Vs[((ch*4+q)*32 + ln)*8];
      bf16x8 bv1 = *(bf16x8*)&Vs[((ch*4+q)*32 + 16 + ln)*8];
      oacc[0] = MFMA16(ap, bv0, oacc[0]);
      oacc[1] = MFMA16(ap, bv1, oacc[1]);
    }
  }
  #pragma unroll
  for (int r=0;r<4;r++) {
    float v = rs[r];
    v += __shfl_xor(v,1); v += __shfl_xor(v,2); v += __shfl_xor(v,4); v += __shfl_xor(v,8);
    rs[r] = __builtin_amdgcn_rcpf(v);
  }
  const int orow = bb*256 + pt*64 + w*16 + q*4;
  #pragma unroll
  for (int dt=0;dt<2;dt++)
    #pragma unroll
    for (int r=0;r<4;r++)
      Og[(orow + r)*512 + h*32 + dt*16 + ln] = f2bf(oacc[dt][r]*rs[r]);
}

// ---------------------------------------------------------------------------
// cmbfin: fused combine-GEMM + pointer-GEMM + tanh-softmax.
// Phase 1: mh[16 x 512] = oc @ WtC + bias (A staged in LDS, B from global),
//          result -> LDS in A-fragment layout (bf16, same rounding as before).
// Phase 2: score2 = mh @ nodes^T, 10*tanh + mask, softmax over full row,
//          store probs. grid = 512 (b x 16 rowgroups), 512 thr (8 waves).
// ---------------------------------------------------------------------------
__global__ __launch_bounds__(512) void cmbfin(const u16* __restrict__ oc, const u16* __restrict__ WtC,
                                              const float* __restrict__ bias,
                                              const u16* __restrict__ nodesb, const u16* __restrict__ maskP,
                                              float* __restrict__ out)
{
  const int bid = blockIdx.x;
  const int rt = bid & 15, bb = bid >> 4;
  const int t = threadIdx.x, w = t >> 6, l = t & 63, q = l >> 4, ln = l & 15;
  __shared__ u16 As[8192];      // oc tile [koct(64)][row(16)][8]
  __shared__ u16 Ms[8192];      // mh tile, same layout (k = combine output col)
  __shared__ float rsL[8][16];
  const int abase = (bb*256 + rt*16)*512;
  #pragma unroll
  for (int c=0;c<2;c++) {
    int chunk = t + 512*c;
    gload16(&oc[abase + (chunk & 15)*512 + (chunk >> 4)*8], &As[chunk*8]);
  }
  __syncthreads();
  // ---- phase 1: combine. wave w covers cols w*64..w*64+63 ----
  f32x4 acc1[4];
  #pragma unroll
  for (int ct=0;ct<4;ct++)
    #pragma unroll
    for (int r=0;r<4;r++) acc1[ct][r] = 0.f;
  for (int kc=0;kc<16;kc++) {
    bf16x8 af = *(bf16x8*)&As[((kc*4 + q)*16 + ln)*8];
    #pragma unroll
    for (int ct=0;ct<4;ct++) {
      int col = w*64 + ct*16 + ln;
      bf16x8 bfr = *(const bf16x8*)&WtC[col*512 + kc*32 + q*8];
      acc1[ct] = MFMA16(af, bfr, acc1[ct]);
    }
  }
  #pragma unroll
  for (int ct=0;ct<4;ct++) {
    int gn = w*64 + ct*16 + ln;
    float bv = bias[gn];
    #pragma unroll
    for (int r=0;r<4;r++) {
      int row = q*4 + r;
      Ms[(gn >> 3)*128 + row*8 + (gn & 7)] = f2bf(acc1[ct][r] + bv);
    }
  }
  __syncthreads();
  // ---- phase 2: pointer logits + softmax. wave w covers cols w*128.. ----
  float rloc[4] = {0.f,0.f,0.f,0.f};
  const int nbase = bb*524288;
  f32x4 acc[8];
  #pragma unroll
  for (int ct=0;ct<8;ct++)
    #pragma unroll
    for (int r=0;r<4;r++) acc[ct][r] = 0.f;
  for (int kc=0;kc<16;kc++) {
    bf16x8 af = *(bf16x8*)&Ms[((kc*4 + q)*16 + ln)*8];
    #pragma unroll
    for (int ct=0;ct<8;ct++) {
      int col = w*128 + ct*16 + ln;
      bf16x8 bfr = *(const bf16x8*)&nodesb[nbase + col*512 + kc*32 + q*8];
      acc[ct] = MFMA16(af, bfr, acc[ct]);
    }
  }
  const float c2 = 0.08838834764831843f;   // 2/sqrt(512)
  const int prow_base = bb*256 + rt*16;
  #pragma unroll
  for (int ct=0;ct<8;ct++) {
    int col0 = w*128 + ct*16 + ln;
    u16x4 mv = *(const u16x4*)&maskP[((bb*16 + rt)*1024 + col0)*16 + q*4];
    #pragma unroll
    for (int r=0;r<4;r++) {
      float x = acc[ct][r] * c2;
      x = fminf(fmaxf(x, -30.f), 30.f);
      float e2 = __expf(x);
      float lg = 10.f*(e2 - 1.f)*__builtin_amdgcn_rcpf(e2 + 1.f) + bf2f(mv[r]);
      float e = __expf(lg);
      rloc[r] += e;
      acc[ct][r] = e;
    }
  }
  #pragma unroll
  for (int r=0;r<4;r++) {
    float v = rloc[r];
    v += __shfl_xor(v,1); v += __shfl_xor(v,2); v += __shfl_xor(v,4); v += __shfl_xor(v,8);
    rloc[r] = v;
  }
  if (ln == 0) {
    #pragma unroll
    for (int r=0;r<4;r++) rsL[w][q*4 + r] = rloc[r];
  }
  __syncthreads();
  float inv[4];
  #pragma unroll
  for (int r=0;r<4;r++) {
    float tot = 0.f;
    #pragma unroll
    for (int ww=0;ww<8;ww++) tot += rsL[ww][q*4 + r];
    inv[r] = __builtin_amdgcn_rcpf(tot);
  }
  #pragma unroll
  for (int ct=0;ct<8;ct++) {
    int col0 = w*128 + ct*16 + ln;
    #pragma unroll
    for (int r=0;r<4;r++)
      out[(prow_base + q*4 + r)*1024 + col0] = acc[ct][r]*inv[r];
  }
}

extern "C" void kernel_launch(void* const* d_in, const int* in_sizes, int n_in,
                              void* d_out, int out_size, void* d_ws, size_t ws_size,
                              hipStream_t stream)
{
  (void)in_sizes; (void)n_in; (void)out_size; (void)ws_size;
  const float* nodes = (const float*)d_in[0];
  const float* q1    = (const float*)d_in[1];
  const float* lastn = (const float*)d_in[2];
  const float* mask  = (const float*)d_in[3];
  const float* Wqf   = (const float*)d_in[4];
  const float* Wql   = (const float*)d_in[5];
  const float* Wk    = (const float*)d_in[6];
  const float* Wv    = (const float*)d_in[7];
  const float* Wc    = (const float*)d_in[8];
  const float* bias  = (const float*)d_in[9];
  float* out = (float*)d_out;

  char* p = (char*)d_ws;
  u16* nodesb = (u16*)p; p += 33554432;   // [32][1024][512] bf16
  u16* q1b    = (u16*)p; p += 8388608;    // [32][256][512]
  u16* lastb  = (u16*)p; p += 8388608;
  u16* WtKV   = (u16*)p; p += 1048576;    // [1024][512]
  u16* WtQF   = (u16*)p; p += 524288;
  u16* WtQL   = (u16*)p; p += 524288;
  u16* WtC    = (u16*)p; p += 524288;
  u16* Kt     = (u16*)p; p += 33554432;   // K [32][16][1024][32]
  u16* Vt     = (u16*)p; p += 33554432;   // V^T [32][16][32][1024]
  u16* Qh     = (u16*)p; p += 8388608;    // Q(scaled) [32][16][256][32]
  u16* maskP  = (u16*)p; p += 16777216;   // [32][16][1024][16] bf16
  u16* oc  = lastb;   // dead after gemm_q

  prep<<<4096, 256, 0, stream>>>(nodes, q1, lastn, mask, Wqf, Wql, Wk, Wv, Wc,
                                 nodesb, q1b, lastb, WtKV, WtQF, WtQL, WtC, maskP);
  gemm_kv<<<2048, 256, 0, stream>>>(nodesb, WtKV, Kt, Vt);
  gemm_q<<<1024, 256, 0, stream>>>(q1b, lastb, WtQF, WtQL, Qh);
  attn<<<2048, 256, 0, stream>>>(Qh, Kt, Vt, maskP, oc);
  cmbfin<<<512, 512, 0, stream>>>(oc, WtC, bias, nodesb, maskP, out);
}

// Round 5
// 397.822 us; speedup vs baseline: 1.1571x; 1.1452x over previous
//
#include <hip/hip_runtime.h>
#include <math.h>

typedef unsigned short u16;
typedef __attribute__((ext_vector_type(8))) short bf16x8;
typedef __attribute__((ext_vector_type(4))) float f32x4;
typedef __attribute__((ext_vector_type(4))) int i32x4;
typedef __attribute__((ext_vector_type(4))) short s16x4;
typedef __attribute__((ext_vector_type(4))) unsigned short u16x4;

#define MFMA16(a,b,c) __builtin_amdgcn_mfma_f32_16x16x32_bf16((a),(b),(c),0,0,0)

__device__ __forceinline__ u16 f2bf(float x){
  unsigned int u = __float_as_uint(x);
  u += 0x7fffu + ((u >> 16) & 1u);   // RNE
  return (u16)(u >> 16);
}
__device__ __forceinline__ float bf2f(u16 x){
  return __uint_as_float(((unsigned)x) << 16);
}
// async global->LDS, 16B per lane. LDS image must be lane-linear.
__device__ __forceinline__ void gload16(const void* g, void* l){
  __builtin_amdgcn_global_load_lds((const __attribute__((address_space(1))) void*)g,
                                   (__attribute__((address_space(3))) void*)l, 16, 0, 0);
}

// ---------------------------------------------------------------------------
// prep: fp32->bf16 + weight transposes + maskP packing.
// maskP[b][rt(16)][col(1024)][p(16)] bf16, p = row-in-16 (MFMA C-layout order).
// grid = 4096 x 256.
// ---------------------------------------------------------------------------
__global__ __launch_bounds__(256) void prep(
    const float* __restrict__ nodes, const float* __restrict__ q1, const float* __restrict__ lastn,
    const float* __restrict__ mask,
    const float* __restrict__ Wqf, const float* __restrict__ Wql, const float* __restrict__ Wk,
    const float* __restrict__ Wv, const float* __restrict__ Wc,
    u16* __restrict__ nodesb, u16* __restrict__ q1b, u16* __restrict__ lastb,
    u16* __restrict__ WtKV, u16* __restrict__ WtQF, u16* __restrict__ WtQL, u16* __restrict__ WtC,
    u16* __restrict__ maskP)
{
  const int tid = blockIdx.x * 256 + threadIdx.x;
  const int NT = 1048576;
  for (int i = tid; i < 4194304; i += NT) {
    float4 v = ((const float4*)nodes)[i];
    u16x4 o; o[0]=f2bf(v.x); o[1]=f2bf(v.y); o[2]=f2bf(v.z); o[3]=f2bf(v.w);
    *(u16x4*)&nodesb[i*4] = o;
  }
  {
    float4 v = ((const float4*)q1)[tid];
    u16x4 o; o[0]=f2bf(v.x); o[1]=f2bf(v.y); o[2]=f2bf(v.z); o[3]=f2bf(v.w);
    *(u16x4*)&q1b[tid*4] = o;
    v = ((const float4*)lastn)[tid];
    o[0]=f2bf(v.x); o[1]=f2bf(v.y); o[2]=f2bf(v.z); o[3]=f2bf(v.w);
    *(u16x4*)&lastb[tid*4] = o;
  }
  if (tid < 262144) {
    int n = tid >> 9, k = tid & 511;
    WtQF[tid] = f2bf(Wqf[k*512 + n]);
    WtQL[tid] = f2bf(Wql[k*512 + n]);
    WtC[tid]  = f2bf(Wc[k*512 + n]);
  }
  if (tid < 524288) {
    int n = tid >> 9, k = tid & 511;
    WtKV[tid] = f2bf(n < 512 ? Wk[k*512 + n] : Wv[k*512 + (n-512)]);
  }
  if (tid < 524288) {  // maskP: tid = (b*16 + rt)*1024 + c
    int brt = tid >> 10, c = tid & 1023;
    const float* mp = mask + (brt*16)*1024 + c;
    u16 vals[16];
    #pragma unroll
    for (int p=0;p<16;p++) vals[p] = f2bf(mp[p*1024]);
    *(i32x4*)&maskP[tid*16]     = *(i32x4*)&vals[0];
    *(i32x4*)&maskP[tid*16 + 8] = *(i32x4*)&vals[8];
  }
}

// ---------------------------------------------------------------------------
// K|V projection GEMM, 128x128 tile, BK=32 double-buffered, LDS-transpose
// epilogue. XCD swizzle: bid = mbhi*64 + nb*8 + mblo -> same-A blocks share
// an XCD within a 64-bid window. grid = 2048.
// ---------------------------------------------------------------------------
__global__ __launch_bounds__(256) void gemm_kv(const u16* __restrict__ A, const u16* __restrict__ Bw,
                                               u16* __restrict__ Kout, u16* __restrict__ Vout)
{
  const int mb = (blockIdx.x >> 6)*8 + (blockIdx.x & 7);
  const int nb = (blockIdx.x >> 3) & 7;
  const int t = threadIdx.x, w = t >> 6, l = t & 63, q = l >> 4, ln = l & 15;
  const int wm = (w >> 1) * 64, wn = (w & 1) * 64;
  __shared__ u16 smem[17920];
  f32x4 acc[4][4];
  #pragma unroll
  for (int i=0;i<4;i++)
    #pragma unroll
    for (int j=0;j<4;j++)
      #pragma unroll
      for (int r=0;r<4;r++) acc[i][j][r] = 0.f;
  const int m0 = mb*128, n0 = nb*128;

  #define STAGE_KV(kc_, b_) { \
    u16* sa = smem + (b_)*8192; \
    u16* sb = sa + 4096; \
    _Pragma("unroll") \
    for (int c=0;c<2;c++){ \
      int chunk = c*256 + t; \
      int ko = chunk >> 7, r_ = chunk & 127; \
      gload16(&A[(m0+r_)*512 + (kc_)*32 + ko*8], &sa[chunk*8]); \
      gload16(&Bw[(n0+r_)*512 + (kc_)*32 + ko*8], &sb[chunk*8]); \
    } }

  STAGE_KV(0, 0);
  for (int kc = 0; kc < 16; kc++) {
    __syncthreads();
    if (kc < 15) STAGE_KV(kc+1, (kc+1)&1);
    const u16* sa = smem + (kc&1)*8192;
    const u16* sb = sa + 4096;
    bf16x8 af[4], bfr[4];
    #pragma unroll
    for (int i=0;i<4;i++) af[i] = *(bf16x8*)&sa[(q*128 + wm + i*16 + ln)*8];
    #pragma unroll
    for (int j=0;j<4;j++) bfr[j] = *(bf16x8*)&sb[(q*128 + wn + j*16 + ln)*8];
    #pragma unroll
    for (int i=0;i<4;i++)
      #pragma unroll
      for (int j=0;j<4;j++)
        acc[i][j] = MFMA16(af[i], bfr[j], acc[i][j]);
  }
  #undef STAGE_KV

  // ---- epilogue: transpose via LDS, then coalesced stores ----
  __syncthreads();
  #pragma unroll
  for (int i=0;i<4;i++) {
    #pragma unroll
    for (int j=0;j<4;j++) {
      s16x4 o;
      #pragma unroll
      for (int r=0;r<4;r++) o[r] = (short)f2bf(acc[i][j][r]);
      *(s16x4*)&smem[(wn + j*16 + ln)*140 + wm + i*16 + q*4] = o;
    }
  }
  __syncthreads();
  const int bb_ = mb >> 3, mloc = (mb & 7)*128;
  if (nb < 4) {
    u16* base = Kout + ((bb_*16 + nb*4 + w)*1024 + mloc)*32;
    #pragma unroll
    for (int it=0; it<8; it++) {
      int idx = it*512 + l*8;
      int m_ = idx >> 5, d0 = idx & 31;
      int col = w*32 + d0;
      u16 v[8];
      #pragma unroll
      for (int dd=0;dd<8;dd++) v[dd] = smem[(col+dd)*140 + m_];
      *(i32x4*)&base[idx] = *(i32x4*)&v[0];
    }
  } else {
    u16* base = Vout + (((bb_*16 + (nb-4)*4 + w)*32))*1024 + mloc;
    #pragma unroll
    for (int it=0; it<8; it++) {
      int d_ = it*4 + (l >> 4);
      int mc_ = (l & 15)*8;
      *(i32x4*)&base[d_*1024 + mc_] = *(i32x4*)&smem[(w*32 + d_)*140 + mc_];
    }
  }
}

// ---------------------------------------------------------------------------
// Q projection, 64x64 tile, BK=64. Q = (q1@Wqf + last@Wql) * (1/sqrt(32)).
// XCD swizzle like gemm_kv. grid = 1024.
// ---------------------------------------------------------------------------
__global__ __launch_bounds__(256) void gemm_q(const u16* __restrict__ A1, const u16* __restrict__ A2,
                                              const u16* __restrict__ B1, const u16* __restrict__ B2,
                                              u16* __restrict__ Qout)
{
  const int mb = (blockIdx.x >> 6)*8 + (blockIdx.x & 7);
  const int nb = (blockIdx.x >> 3) & 7;
  const int t = threadIdx.x, w = t >> 6, l = t & 63, q = l >> 4, ln = l & 15;
  const int wm = (w >> 1) * 32, wn = (w & 1) * 32;
  __shared__ u16 As[4096];   // [koct(8)][row(64)][8]
  __shared__ u16 Bs[4096];
  f32x4 acc[2][2];
  #pragma unroll
  for (int i=0;i<2;i++)
    #pragma unroll
    for (int j=0;j<2;j++)
      #pragma unroll
      for (int r=0;r<4;r++) acc[i][j][r] = 0.f;
  const int m0 = mb*64, n0 = nb*64;
  for (int kc = 0; kc < 16; kc++) {
    const u16* Ap = (kc < 8) ? A1 : A2;
    const u16* Bp = (kc < 8) ? B1 : B2;
    const int k0 = (kc & 7) * 64;
    __syncthreads();
    #pragma unroll
    for (int c=0;c<2;c++) {
      int chunk = t + 256*c;
      int row = chunk & 63, ko = chunk >> 6;
      gload16(&Ap[(m0+row)*512 + k0 + ko*8], &As[chunk*8]);
      gload16(&Bp[(n0+row)*512 + k0 + ko*8], &Bs[chunk*8]);
    }
    __syncthreads();
    #pragma unroll
    for (int ko=0;ko<2;ko++) {
      bf16x8 af[2], bfr[2];
      #pragma unroll
      for (int i=0;i<2;i++) af[i] = *(bf16x8*)&As[((ko*4+q)*64 + wm + i*16 + ln)*8];
      #pragma unroll
      for (int j=0;j<2;j++) bfr[j] = *(bf16x8*)&Bs[((ko*4+q)*64 + wn + j*16 + ln)*8];
      #pragma unroll
      for (int i=0;i<2;i++)
        #pragma unroll
        for (int j=0;j<2;j++)
          acc[i][j] = MFMA16(af[i], bfr[j], acc[i][j]);
    }
  }
  const float sc = 0.17677669529663687f;
  #pragma unroll
  for (int i=0;i<2;i++) {
    int gm = m0 + wm + i*16 + q*4;
    int bb = gm >> 8, pm = gm & 255;
    #pragma unroll
    for (int j=0;j<2;j++) {
      int gn = n0 + wn + j*16 + ln;
      int h = gn >> 5, d = gn & 31;
      u16* qp = Qout + ((bb*16 + h)*256 + pm)*32 + d;
      #pragma unroll
      for (int r=0;r<4;r++) qp[r*32] = f2bf(acc[i][j][r]*sc);
    }
  }
}

// ---------------------------------------------------------------------------
// Fused attention per (b, h, pomo64). grid = 2048, 4 waves.
// XCD swizzle: bid = bhhi*32 + pt*8 + bhlo -> 4 pt-blocks sharing K/V on one
// XCD within a 32-bid window.
// ---------------------------------------------------------------------------
__global__ __launch_bounds__(256) void attn(const u16* __restrict__ Qg, const u16* __restrict__ Kg,
                                            const u16* __restrict__ Vtg, const u16* __restrict__ maskP,
                                            u16* __restrict__ Og)
{
  const int bid = blockIdx.x;
  const int bh = (bid >> 5)*8 + (bid & 7);       // 0..511
  const int pt = (bid >> 3) & 3;
  const int h = bh & 15, bb = bh >> 4;
  const int t = threadIdx.x, w = t >> 6, l = t & 63, q = l >> 4, ln = l & 15;
  __shared__ u16 Qs[2048];     // [qk(4)][row(64)][8]
  __shared__ u16 Ks[4096];     // [qk(4)][m(128)][8]
  __shared__ u16 Vs[4096];     // [moct(16)][d(32)][8]
  __shared__ u16 Ps[4*640];    // per wave [16][40]
  u16* Pw = &Ps[w*640];
  const int qbase = ((bb*16 + h)*256 + pt*64)*32;
  gload16(&Qg[qbase + (t & 63)*32 + (t >> 6)*8], &Qs[t*8]);
  const int kbase = (bb*16 + h)*1024*32;
  const int vbase = (bb*16 + h)*32*1024;
  float rs[4] = {0.f,0.f,0.f,0.f};
  f32x4 oacc[2];
  #pragma unroll
  for (int dt=0;dt<2;dt++)
    #pragma unroll
    for (int r=0;r<4;r++) oacc[dt][r] = 0.f;
  __syncthreads();
  const bf16x8 aq = *(bf16x8*)&Qs[(q*64 + w*16 + ln)*8];
  const u16* mrow = maskP + (bb*16 + pt*4 + w)*16384 + q*4;
  for (int mc = 0; mc < 8; mc++) {
    __syncthreads();
    gload16(&Kg[kbase + (mc*128 + (t & 127))*32 + (t >> 7)*8],       &Ks[t*8]);
    gload16(&Kg[kbase + (mc*128 + (t & 127))*32 + ((t >> 7)+2)*8],   &Ks[(t+256)*8]);
    gload16(&Vtg[vbase + (t & 31)*1024 + mc*128 + (t >> 5)*8],       &Vs[t*8]);
    gload16(&Vtg[vbase + (t & 31)*1024 + mc*128 + ((t >> 5)+8)*8],   &Vs[(t+256)*8]);
    u16x4 mq[8];
    #pragma unroll
    for (int j2=0;j2<8;j2++)
      mq[j2] = *(const u16x4*)&mrow[(mc*128 + j2*16 + ln)*16];
    __syncthreads();
    #pragma unroll
    for (int ch=0; ch<4; ch++) {
      bf16x8 bk0 = *(bf16x8*)&Ks[(q*128 + (ch*2+0)*16 + ln)*8];
      bf16x8 bk1 = *(bf16x8*)&Ks[(q*128 + (ch*2+1)*16 + ln)*8];
      f32x4 zz = {0.f,0.f,0.f,0.f};
      f32x4 s0 = MFMA16(aq, bk0, zz);
      f32x4 s1 = MFMA16(aq, bk1, zz);
      #pragma unroll
      for (int r=0;r<4;r++) {
        float e0 = __expf(s0[r] + bf2f(mq[ch*2+0][r]));
        float e1 = __expf(s1[r] + bf2f(mq[ch*2+1][r]));
        rs[r] += e0 + e1;
        Pw[(q*4+r)*40 + ln]      = f2bf(e0);
        Pw[(q*4+r)*40 + 16 + ln] = f2bf(e1);
      }
      bf16x8 ap  = *(bf16x8*)&Pw[ln*40 + q*8];
      bf16x8 bv0 = *(bf16x8*)&Vs[((ch*4+q)*32 + ln)*8];
      bf16x8 bv1 = *(bf16x8*)&Vs[((ch*4+q)*32 + 16 + ln)*8];
      oacc[0] = MFMA16(ap, bv0, oacc[0]);
      oacc[1] = MFMA16(ap, bv1, oacc[1]);
    }
  }
  #pragma unroll
  for (int r=0;r<4;r++) {
    float v = rs[r];
    v += __shfl_xor(v,1); v += __shfl_xor(v,2); v += __shfl_xor(v,4); v += __shfl_xor(v,8);
    rs[r] = __builtin_amdgcn_rcpf(v);
  }
  const int orow = bb*256 + pt*64 + w*16 + q*4;
  #pragma unroll
  for (int dt=0;dt<2;dt++)
    #pragma unroll
    for (int r=0;r<4;r++)
      Og[(orow + r)*512 + h*32 + dt*16 + ln] = f2bf(oacc[dt][r]*rs[r]);
}

// ---------------------------------------------------------------------------
// cmbfin: fused combine-GEMM + pointer-GEMM + tanh-softmax.
// 1024 threads (16 waves), 32 rows x 1024 cols per block, grid = 256
// (1 block/CU). XCD swizzle: bid = rg*32 + bb -> all 8 row-groups of batch b
// on one XCD (nodesb[b] = 1 MB stays in that XCD's L2; 4 b's = 4 MB = L2).
// ---------------------------------------------------------------------------
__global__ __launch_bounds__(1024) void cmbfin(const u16* __restrict__ oc, const u16* __restrict__ WtC,
                                               const float* __restrict__ bias,
                                               const u16* __restrict__ nodesb, const u16* __restrict__ maskP,
                                               float* __restrict__ out)
{
  const int bid = blockIdx.x;
  const int bb = bid & 31, rg = bid >> 5;     // rg 0..7: 32-row group
  const int t = threadIdx.x, w = t >> 6, l = t & 63, q = l >> 4, ln = l & 15;
  __shared__ u16 As[16384];     // oc tile [koct(64)][row(32)][8]
  __shared__ u16 Ms[16384];     // mh tile, same layout (k = combine out col)
  __shared__ float rsL[16][32];
  const int abase = (bb*256 + rg*32)*512;
  #pragma unroll
  for (int c=0;c<2;c++) {
    int chunk = t + 1024*c;
    gload16(&oc[abase + (chunk & 31)*512 + (chunk >> 5)*8], &As[chunk*8]);
  }
  __syncthreads();
  // ---- phase 1: combine. wave w covers cols w*32..w*32+31 ----
  f32x4 acc1[2][2];
  #pragma unroll
  for (int i=0;i<2;i++)
    #pragma unroll
    for (int ct=0;ct<2;ct++)
      #pragma unroll
      for (int r=0;r<4;r++) acc1[i][ct][r] = 0.f;
  for (int kc=0;kc<16;kc++) {
    bf16x8 af[2];
    #pragma unroll
    for (int i=0;i<2;i++) af[i] = *(bf16x8*)&As[((kc*4 + q)*32 + i*16 + ln)*8];
    #pragma unroll
    for (int ct=0;ct<2;ct++) {
      int col = w*32 + ct*16 + ln;
      bf16x8 bfr = *(const bf16x8*)&WtC[col*512 + kc*32 + q*8];
      #pragma unroll
      for (int i=0;i<2;i++) acc1[i][ct] = MFMA16(af[i], bfr, acc1[i][ct]);
    }
  }
  #pragma unroll
  for (int ct=0;ct<2;ct++) {
    int gn = w*32 + ct*16 + ln;
    float bv = bias[gn];
    #pragma unroll
    for (int i=0;i<2;i++)
      #pragma unroll
      for (int r=0;r<4;r++)
        Ms[(gn >> 3)*256 + (i*16 + q*4 + r)*8 + (gn & 7)] = f2bf(acc1[i][ct][r] + bv);
  }
  __syncthreads();
  // ---- phase 2: pointer logits + softmax. wave w covers cols w*64.. ----
  float rloc[2][4] = {{0.f,0.f,0.f,0.f},{0.f,0.f,0.f,0.f}};
  const int nbase = bb*524288;
  f32x4 acc[2][4];
  #pragma unroll
  for (int i=0;i<2;i++)
    #pragma unroll
    for (int ct=0;ct<4;ct++)
      #pragma unroll
      for (int r=0;r<4;r++) acc[i][ct][r] = 0.f;
  for (int kc=0;kc<16;kc++) {
    bf16x8 af[2];
    #pragma unroll
    for (int i=0;i<2;i++) af[i] = *(bf16x8*)&Ms[((kc*4 + q)*32 + i*16 + ln)*8];
    #pragma unroll
    for (int ct=0;ct<4;ct++) {
      int col = w*64 + ct*16 + ln;
      bf16x8 bfr = *(const bf16x8*)&nodesb[nbase + col*512 + kc*32 + q*8];
      #pragma unroll
      for (int i=0;i<2;i++) acc[i][ct] = MFMA16(af[i], bfr, acc[i][ct]);
    }
  }
  const float c2 = 0.08838834764831843f;   // 2/sqrt(512)
  const int prow_base = bb*256 + rg*32;
  #pragma unroll
  for (int i=0;i<2;i++) {
    #pragma unroll
    for (int ct=0;ct<4;ct++) {
      int col0 = w*64 + ct*16 + ln;
      u16x4 mv = *(const u16x4*)&maskP[((bb*16 + rg*2 + i)*1024 + col0)*16 + q*4];
      #pragma unroll
      for (int r=0;r<4;r++) {
        float x = acc[i][ct][r] * c2;
        x = fminf(fmaxf(x, -30.f), 30.f);
        float e2 = __expf(x);
        float lg = 10.f*(e2 - 1.f)*__builtin_amdgcn_rcpf(e2 + 1.f) + bf2f(mv[r]);
        float e = __expf(lg);
        rloc[i][r] += e;
        acc[i][ct][r] = e;
      }
    }
  }
  #pragma unroll
  for (int i=0;i<2;i++)
    #pragma unroll
    for (int r=0;r<4;r++) {
      float v = rloc[i][r];
      v += __shfl_xor(v,1); v += __shfl_xor(v,2); v += __shfl_xor(v,4); v += __shfl_xor(v,8);
      rloc[i][r] = v;
    }
  if (ln == 0) {
    #pragma unroll
    for (int i=0;i<2;i++)
      #pragma unroll
      for (int r=0;r<4;r++) rsL[w][i*16 + q*4 + r] = rloc[i][r];
  }
  __syncthreads();
  float inv[2][4];
  #pragma unroll
  for (int i=0;i<2;i++)
    #pragma unroll
    for (int r=0;r<4;r++) {
      float tot = 0.f;
      #pragma unroll
      for (int ww=0;ww<16;ww++) tot += rsL[ww][i*16 + q*4 + r];
      inv[i][r] = __builtin_amdgcn_rcpf(tot);
    }
  #pragma unroll
  for (int i=0;i<2;i++)
    #pragma unroll
    for (int ct=0;ct<4;ct++) {
      int col0 = w*64 + ct*16 + ln;
      #pragma unroll
      for (int r=0;r<4;r++)
        out[(prow_base + i*16 + q*4 + r)*1024 + col0] = acc[i][ct][r]*inv[i][r];
    }
}

extern "C" void kernel_launch(void* const* d_in, const int* in_sizes, int n_in,
                              void* d_out, int out_size, void* d_ws, size_t ws_size,
                              hipStream_t stream)
{
  (void)in_sizes; (void)n_in; (void)out_size; (void)ws_size;
  const float* nodes = (const float*)d_in[0];
  const float* q1    = (const float*)d_in[1];
  const float* lastn = (const float*)d_in[2];
  const float* mask  = (const float*)d_in[3];
  const float* Wqf   = (const float*)d_in[4];
  const float* Wql   = (const float*)d_in[5];
  const float* Wk    = (const float*)d_in[6];
  const float* Wv    = (const float*)d_in[7];
  const float* Wc    = (const float*)d_in[8];
  const float* bias  = (const float*)d_in[9];
  float* out = (float*)d_out;

  char* p = (char*)d_ws;
  u16* nodesb = (u16*)p; p += 33554432;   // [32][1024][512] bf16
  u16* q1b    = (u16*)p; p += 8388608;    // [32][256][512]
  u16* lastb  = (u16*)p; p += 8388608;
  u16* WtKV   = (u16*)p; p += 1048576;    // [1024][512]
  u16* WtQF   = (u16*)p; p += 524288;
  u16* WtQL   = (u16*)p; p += 524288;
  u16* WtC    = (u16*)p; p += 524288;
  u16* Kt     = (u16*)p; p += 33554432;   // K [32][16][1024][32]
  u16* Vt     = (u16*)p; p += 33554432;   // V^T [32][16][32][1024]
  u16* Qh     = (u16*)p; p += 8388608;    // Q(scaled) [32][16][256][32]
  u16* maskP  = (u16*)p; p += 16777216;   // [32][16][1024][16] bf16
  u16* oc  = lastb;   // dead after gemm_q

  prep<<<4096, 256, 0, stream>>>(nodes, q1, lastn, mask, Wqf, Wql, Wk, Wv, Wc,
                                 nodesb, q1b, lastb, WtKV, WtQF, WtQL, WtC, maskP);
  gemm_kv<<<2048, 256, 0, stream>>>(nodesb, WtKV, Kt, Vt);
  gemm_q<<<1024, 256, 0, stream>>>(q1b, lastb, WtQF, WtQL, Qh);
  attn<<<2048, 256, 0, stream>>>(Qh, Kt, Vt, maskP, oc);
  cmbfin<<<256, 1024, 0, stream>>>(oc, WtC, bias, nodesb, maskP, out);
}